// Round 15
// baseline (396.384 us; speedup 1.0000x reference)
//
#include <hip/hip_runtime.h>

#define NN    50000
#define EE    800000
#define EPE   850000     // EE + NN self loops
#define NPAD  50048      // multiple of 64
#define BGR   64
#define MAXCH 128        // edge chunk per node held in LDS (aggregate)
#define NB    98         // buckets of 512 nodes
#define CHUNK 4096       // edges per binning block
#define NBLK  208        // ceil(EPE / CHUNK)
#define BCAP  12288      // per-bucket LDS capacity in build_csr

typedef __attribute__((ext_vector_type(8))) short bf16x8;
typedef __attribute__((ext_vector_type(4))) float f32x4;
typedef __attribute__((ext_vector_type(2))) float f32x2;

__device__ __forceinline__ float bf2f(unsigned short u) {
    return __uint_as_float(((unsigned)u) << 16);
}
__device__ __forceinline__ unsigned short f2bf(float f) {
    unsigned u = __float_as_uint(f);
    unsigned r = (u + 0x7FFFu + ((u >> 16) & 1u)) >> 16;
    return (unsigned short)r;
}
__device__ __forceinline__ float silu(float y) { return y / (1.f + __expf(-y)); }

// -- fused: weight transpose (blk 0-3) + pooled zero (blk 4..35) --
__global__ void transpose_zero(const float* __restrict__ W0, const float* __restrict__ Wg,
                               unsigned short* __restrict__ WT, float* __restrict__ pooled) {
    __shared__ unsigned short tile[128][129];
    int b = blockIdx.x;
    if (b < 4) {
        const float* src = (b == 0) ? W0 : (Wg + (b - 1) * 16384);
        unsigned short* dst = WT + b * 16384;
        for (int i = threadIdx.x; i < 16384; i += 256) tile[i >> 7][i & 127] = f2bf(src[i]);
        __syncthreads();
        for (int i = threadIdx.x; i < 16384; i += 256) {
            int c = i >> 7, k = i & 127;
            dst[i] = tile[k][c];
        }
    } else {
        int j = (b - 4) * 256 + threadIdx.x;
        if (j < BGR * 128) pooled[j] = 0.f;
    }
}

// ---------------- per-chunk bucket histograms (LDS only, no global atomics) -----------
__global__ __launch_bounds__(256) void bucket_hist(const int* __restrict__ eidx,
                                                   int* __restrict__ hist_blk) {
    __shared__ int lh[NB];
    for (int t = threadIdx.x; t < NB; t += 256) lh[t] = 0;
    __syncthreads();
    int base = blockIdx.x * CHUNK;
#pragma unroll
    for (int j = 0; j < CHUNK / 256; ++j) {
        int i = base + j * 256 + threadIdx.x;
        if (i < EPE) {
            int d = (i < EE) ? eidx[EE + i] : (i - EE);
            atomicAdd(&lh[d >> 9], 1);
        }
    }
    __syncthreads();
    for (int t = threadIdx.x; t < NB; t += 256)
        hist_blk[blockIdx.x * NB + t] = lh[t];
}

// ------- bucket totals -> per-block per-bucket offsets + bucketBase -------------------
__global__ void scan_buckets(const int* __restrict__ hist_blk, int* __restrict__ blkOfs,
                             int* __restrict__ bucketBase) {
    __shared__ int tot[NB];
    __shared__ int base[NB];
    int t = threadIdx.x;
    if (t < NB) {
        int s = 0;
        for (int k = 0; k < NBLK; ++k) s += hist_blk[k * NB + t];
        tot[t] = s;
    }
    __syncthreads();
    if (t == 0) {
        int run = 0;
        for (int b = 0; b < NB; ++b) { base[b] = run; run += tot[b]; }
        bucketBase[NB] = EPE;
    }
    __syncthreads();
    if (t < NB) {
        int run = base[t];
        bucketBase[t] = run;
        for (int k = 0; k < NBLK; ++k) {
            blkOfs[k * NB + t] = run;
            run += hist_blk[k * NB + t];
        }
    }
}

// ---------------- bin edges into bucket-grouped array (no global atomics) ----------
__global__ __launch_bounds__(256) void bin_edges(const int* __restrict__ eidx,
                                                 const int* __restrict__ blkOfs,
                                                 unsigned* __restrict__ binned) {
    __shared__ unsigned staged[CHUNK];
    __shared__ int lhist[NB];
    __shared__ int lscan[NB];
    __shared__ int cnt2[NB];
    __shared__ int gofs[NB];
    int tid = threadIdx.x;
    for (int t = tid; t < NB; t += 256) { lhist[t] = 0; cnt2[t] = 0; }
    __syncthreads();
    int base = blockIdx.x * CHUNK;
    unsigned pk[CHUNK / 256];
#pragma unroll
    for (int j = 0; j < CHUNK / 256; ++j) {
        int i = base + j * 256 + tid;
        pk[j] = 0xFFFFFFFFu;
        if (i < EPE) {
            int s, d;
            if (i < EE) { s = eidx[i]; d = eidx[EE + i]; } else { s = i - EE; d = i - EE; }
            pk[j] = ((unsigned)s << 16) | (unsigned)d;
            atomicAdd(&lhist[d >> 9], 1);
        }
    }
    __syncthreads();
    if (tid == 0) {
        int run = 0;
        for (int b = 0; b < NB; ++b) { lscan[b] = run; run += lhist[b]; }
    }
    __syncthreads();
#pragma unroll
    for (int j = 0; j < CHUNK / 256; ++j) {
        if (pk[j] != 0xFFFFFFFFu) {
            int b = (int)((pk[j] & 0xFFFFu) >> 9);
            int lp = lscan[b] + atomicAdd(&cnt2[b], 1);
            staged[lp] = pk[j];
        }
    }
    for (int t = tid; t < NB; t += 256) gofs[t] = blkOfs[blockIdx.x * NB + t];
    __syncthreads();
    int nTot = lscan[NB - 1] + lhist[NB - 1];
    for (int i = tid; i < nTot; i += 256) {
        unsigned p = staged[i];
        int b = (int)((p & 0xFFFFu) >> 9);
        binned[gofs[b] + (i - lscan[b])] = p;
    }
}

// ------- per-bucket: local node counts -> offs + in-LDS sort -> contiguous csr --------
__global__ __launch_bounds__(256) void build_csr(const unsigned* __restrict__ binned,
                                                 const int* __restrict__ bucketBase,
                                                 int* __restrict__ offs,
                                                 int* __restrict__ csr) {
    __shared__ int lcsr[BCAP];
    __shared__ int lcnt[512];
    __shared__ int lofs[512];
    __shared__ int lcur[512];
    __shared__ int psum[256];
    int b = blockIdx.x, tid = threadIdx.x;
    int n0 = b * 512;
    int o0 = bucketBase[b];
    int nTot = bucketBase[b + 1] - o0;
    if (nTot > BCAP) nTot = BCAP;
    for (int j = tid; j < 512; j += 256) lcnt[j] = 0;
    __syncthreads();
    for (int i = tid; i < nTot; i += 256)
        atomicAdd(&lcnt[binned[o0 + i] & 511u], 1);
    __syncthreads();
    int a0 = lcnt[2 * tid], a1 = lcnt[2 * tid + 1];
    psum[tid] = a0 + a1;
    __syncthreads();
    for (int d = 1; d < 256; d <<= 1) {
        int v = (tid >= d) ? psum[tid - d] : 0;
        __syncthreads(); psum[tid] += v; __syncthreads();
    }
    int exclPair = psum[tid] - (a0 + a1);
    lofs[2 * tid] = exclPair;
    lofs[2 * tid + 1] = exclPair + a0;
    lcur[2 * tid] = exclPair;
    lcur[2 * tid + 1] = exclPair + a0;
    __syncthreads();
    for (int j = tid; j < 512; j += 256) {
        int node = n0 + j;
        if (node < NN) offs[node] = o0 + lofs[j];
    }
    if (b == 0 && tid == 0) offs[NN] = EPE;
    for (int i = tid; i < nTot; i += 256) {
        unsigned p = binned[o0 + i];
        int pos = atomicAdd(&lcur[p & 511u], 1);
        if (pos < BCAP) lcsr[pos] = (int)(p >> 16);
    }
    __syncthreads();
    for (int i = tid; i < nTot; i += 256)
        csr[o0 + i] = lcsr[i];
}

// ---------------- encoder GEMM: h(bf16) = silu(LN(x@W0 + b0)) ----------------
__global__ __launch_bounds__(256) void gemm_encoder(
    const float* __restrict__ x, const unsigned short* __restrict__ WT,
    const float* __restrict__ b0, const float* __restrict__ g0,
    const float* __restrict__ be0, unsigned short* __restrict__ h) {
    int wave = threadIdx.x >> 6, lane = threadIdx.x & 63;
    int cl = lane & 15, q = lane >> 4;
    int row0 = blockIdx.x * 64 + wave * 16;
    int rA = row0 + cl; if (rA >= NN) rA = NN - 1;
    int kq = q * 8;
    f32x4 acc[8];
#pragma unroll
    for (int t = 0; t < 8; ++t) acc[t] = (f32x4){0.f, 0.f, 0.f, 0.f};
#pragma unroll
    for (int k0 = 0; k0 < 128; k0 += 32) {
        const float* xr = x + rA * 128 + k0 + kq;
        f32x4 f0 = *(const f32x4*)(xr);
        f32x4 f1 = *(const f32x4*)(xr + 4);
        bf16x8 a;
#pragma unroll
        for (int j = 0; j < 4; ++j) {
            a[j] = (short)f2bf(f0[j]);
            a[4 + j] = (short)f2bf(f1[j]);
        }
#pragma unroll
        for (int t = 0; t < 8; ++t) {
            bf16x8 b = *(const bf16x8*)(WT + (t * 16 + cl) * 128 + k0 + kq);
            acc[t] = __builtin_amdgcn_mfma_f32_16x16x32_bf16(a, b, acc[t], 0, 0, 0);
        }
    }
    float bcol[8], gcol[8], becol[8];
#pragma unroll
    for (int t = 0; t < 8; ++t) {
        int c = t * 16 + cl;
        bcol[t] = b0[c]; gcol[t] = g0[c]; becol[t] = be0[c];
    }
#pragma unroll
    for (int r = 0; r < 4; ++r) {
        int row = row0 + q * 4 + r;
        float v[8], s = 0.f, ss = 0.f;
#pragma unroll
        for (int t = 0; t < 8; ++t) {
            v[t] = acc[t][r] + bcol[t];
            s += v[t]; ss += v[t] * v[t];
        }
#pragma unroll
        for (int m = 1; m <= 8; m <<= 1) {
            s += __shfl_xor(s, m, 64); ss += __shfl_xor(ss, m, 64);
        }
        float mu = s * (1.f / 128.f);
        float var = ss * (1.f / 128.f) - mu * mu;
        float rstd = rsqrtf(var + 1e-5f);
        if (row < NN) {
#pragma unroll
            for (int t = 0; t < 8; ++t) {
                float y = (v[t] - mu) * rstd * gcol[t] + becol[t];
                h[row * 128 + t * 16 + cl] = f2bf(silu(y));
            }
        }
    }
}

// ---------------- GAT GEMM: hh(fp8 e4m3) = h@Wg[l], a_s/a_d/es per node --------------
__global__ __launch_bounds__(256) void gemm_gat(
    const unsigned short* __restrict__ h, const unsigned short* __restrict__ WT,
    const float* __restrict__ atts, const float* __restrict__ attd,
    unsigned char* __restrict__ hh8, float* __restrict__ a_s, float* __restrict__ a_d,
    float* __restrict__ es) {
    int wave = threadIdx.x >> 6, lane = threadIdx.x & 63;
    int cl = lane & 15, q = lane >> 4;
    int row0 = blockIdx.x * 64 + wave * 16;
    int rA = row0 + cl; if (rA >= NN) rA = NN - 1;
    int kq = q * 8;
    f32x4 acc[8];
#pragma unroll
    for (int t = 0; t < 8; ++t) acc[t] = (f32x4){0.f, 0.f, 0.f, 0.f};
#pragma unroll
    for (int k0 = 0; k0 < 128; k0 += 32) {
        bf16x8 a = *(const bf16x8*)(h + rA * 128 + k0 + kq);
#pragma unroll
        for (int t = 0; t < 8; ++t) {
            bf16x8 b = *(const bf16x8*)(WT + (t * 16 + cl) * 128 + k0 + kq);
            acc[t] = __builtin_amdgcn_mfma_f32_16x16x32_bf16(a, b, acc[t], 0, 0, 0);
        }
    }
#pragma unroll
    for (int r = 0; r < 4; ++r) {
        int row = row0 + q * 4 + r;
        if (row < NN) {
#pragma unroll
            for (int t = 0; t < 8; ++t) {
                unsigned pk = (unsigned)__builtin_amdgcn_cvt_pk_fp8_f32(acc[t][r], acc[t][r], 0, false);
                hh8[row * 128 + t * 16 + cl] = (unsigned char)(pk & 0xFFu);
            }
        }
    }
    float as_lo[4], as_hi[4], ad_lo[4], ad_hi[4];
#pragma unroll
    for (int hd = 0; hd < 4; ++hd) {
        as_lo[hd] = atts[hd * 32 + cl];      as_hi[hd] = atts[hd * 32 + 16 + cl];
        ad_lo[hd] = attd[hd * 32 + cl];      ad_hi[hd] = attd[hd * 32 + 16 + cl];
    }
#pragma unroll
    for (int r = 0; r < 4; ++r) {
        int row = row0 + q * 4 + r;
        float ps[4], pd[4];
#pragma unroll
        for (int hd = 0; hd < 4; ++hd) {
            float v0 = acc[2 * hd][r], v1 = acc[2 * hd + 1][r];
            ps[hd] = v0 * as_lo[hd] + v1 * as_hi[hd];
            pd[hd] = v0 * ad_lo[hd] + v1 * ad_hi[hd];
        }
#pragma unroll
        for (int m = 1; m <= 8; m <<= 1) {
#pragma unroll
            for (int hd = 0; hd < 4; ++hd) {
                ps[hd] += __shfl_xor(ps[hd], m, 64);
                pd[hd] += __shfl_xor(pd[hd], m, 64);
            }
        }
        if (row < NN && cl < 4) {
            float vs = (cl == 0) ? ps[0] : (cl == 1) ? ps[1] : (cl == 2) ? ps[2] : ps[3];
            float vd = (cl == 0) ? pd[0] : (cl == 1) ? pd[1] : (cl == 2) ? pd[2] : pd[3];
            a_s[row * 4 + cl] = vs;
            a_d[row * 4 + cl] = vd;
            float e = vs + vd;                       // self-loop logit
            es[row * 4 + cl] = (e > 0.f) ? e : 0.2f * e;
        }
    }
}

// ------- aggregation: 4 nodes per wave (16/block), 8 fp8 cols/lane, LDS weights -------
__global__ __launch_bounds__(256) void gat_aggregate(
    const int* __restrict__ offs, const int* __restrict__ csr,
    const float* __restrict__ a_s, const float* __restrict__ a_d,
    const float* __restrict__ es, const unsigned char* __restrict__ hh8,
    unsigned short* __restrict__ h,
    const float* __restrict__ bg, const float* __restrict__ gg,
    const float* __restrict__ bgg) {
    __shared__ f32x4 lw[16][MAXCH];
    int wv = threadIdx.x >> 6;
    int lane = threadIdx.x & 63;
    int quarter = lane >> 4;            // which node of the wave (0..3)
    int l16 = lane & 15;
    int ns = wv * 4 + quarter;          // node slot in block (0..15)
    int node = blockIdx.x * 16 + ns;    // NN % 16 == 0
    int e0 = offs[node], e1 = offs[node + 1];
    int c0 = l16 * 8;                   // 8 columns per lane
    int hd = l16 >> 2;                  // head of this lane's columns
    f32x4 ad4 = *(const f32x4*)(a_d + node * 4);
    f32x4 e4  = *(const f32x4*)(es  + node * 4);
    float dacc[4];
    f32x4 xlo[4], xhi[4];
#pragma unroll
    for (int u = 0; u < 4; ++u) {
        dacc[u] = 0.f;
        xlo[u] = (f32x4){0.f, 0.f, 0.f, 0.f};
        xhi[u] = (f32x4){0.f, 0.f, 0.f, 0.f};
    }
    for (int base = e0; base < e1; base += MAXCH) {
        int cend = min(e1, base + MAXCH);
        // phase A: 16 lanes of this node compute softmax weights (all 4 heads)
        for (int e = base + l16; e < cend; e += 16) {
            int s = csr[e];
            f32x4 as = *(const f32x4*)(a_s + s * 4);
            f32x4 o;
#pragma unroll
            for (int k = 0; k < 4; ++k) {
                float qq = as[k] + ad4[k];
                qq = (qq > 0.f) ? qq : 0.2f * qq;
                o[k] = __expf(qq - e4[k]);
            }
            lw[ns][e - base] = o;
        }
        asm volatile("s_waitcnt lgkmcnt(0)" ::: "memory");
        // phase B: serial weighted accumulation, 4 independent chains
        int n = cend - base;
        int j = 0;
        for (; j + 4 <= n; j += 4) {
            int s0 = csr[base + j], s1 = csr[base + j + 1];
            int s2 = csr[base + j + 2], s3 = csr[base + j + 3];
            float w0 = lw[ns][j + 0][hd];
            float w1 = lw[ns][j + 1][hd];
            float w2 = lw[ns][j + 2][hd];
            float w3 = lw[ns][j + 3][hd];
            uint2 v0 = *(const uint2*)(hh8 + s0 * 128 + c0);
            uint2 v1 = *(const uint2*)(hh8 + s1 * 128 + c0);
            uint2 v2 = *(const uint2*)(hh8 + s2 * 128 + c0);
            uint2 v3 = *(const uint2*)(hh8 + s3 * 128 + c0);
#pragma unroll
            for (int u = 0; u < 4; ++u) {
                uint2 v = (u == 0) ? v0 : (u == 1) ? v1 : (u == 2) ? v2 : v3;
                float w = (u == 0) ? w0 : (u == 1) ? w1 : (u == 2) ? w2 : w3;
                f32x2 p0 = __builtin_amdgcn_cvt_pk_f32_fp8(v.x, false);
                f32x2 p1 = __builtin_amdgcn_cvt_pk_f32_fp8(v.x, true);
                f32x2 p2 = __builtin_amdgcn_cvt_pk_f32_fp8(v.y, false);
                f32x2 p3 = __builtin_amdgcn_cvt_pk_f32_fp8(v.y, true);
                dacc[u] += w;
                xlo[u][0] += w * p0[0]; xlo[u][1] += w * p0[1];
                xlo[u][2] += w * p1[0]; xlo[u][3] += w * p1[1];
                xhi[u][0] += w * p2[0]; xhi[u][1] += w * p2[1];
                xhi[u][2] += w * p3[0]; xhi[u][3] += w * p3[1];
            }
        }
        for (; j < n; ++j) {
            int s0 = csr[base + j];
            float w0 = lw[ns][j][hd];
            uint2 v0 = *(const uint2*)(hh8 + s0 * 128 + c0);
            f32x2 p0 = __builtin_amdgcn_cvt_pk_f32_fp8(v0.x, false);
            f32x2 p1 = __builtin_amdgcn_cvt_pk_f32_fp8(v0.x, true);
            f32x2 p2 = __builtin_amdgcn_cvt_pk_f32_fp8(v0.y, false);
            f32x2 p3 = __builtin_amdgcn_cvt_pk_f32_fp8(v0.y, true);
            dacc[0] += w0;
            xlo[0][0] += w0 * p0[0]; xlo[0][1] += w0 * p0[1];
            xlo[0][2] += w0 * p1[0]; xlo[0][3] += w0 * p1[1];
            xhi[0][0] += w0 * p2[0]; xhi[0][1] += w0 * p2[1];
            xhi[0][2] += w0 * p3[0]; xhi[0][3] += w0 * p3[1];
        }
        if (cend < e1)
            asm volatile("s_waitcnt lgkmcnt(0)" ::: "memory");
    }
    float den = (dacc[0] + dacc[1]) + (dacc[2] + dacc[3]);
    float inv = 1.f / den;
    float o[8];
    float s = 0.f, ss = 0.f;
#pragma unroll
    for (int k = 0; k < 4; ++k) {
        float XL = (xlo[0][k] + xlo[1][k]) + (xlo[2][k] + xlo[3][k]);
        float XH = (xhi[0][k] + xhi[1][k]) + (xhi[2][k] + xhi[3][k]);
        o[k]     = XL * inv + bg[c0 + k];
        o[4 + k] = XH * inv + bg[c0 + 4 + k];
    }
#pragma unroll
    for (int k = 0; k < 8; ++k) { s += o[k]; ss += o[k] * o[k]; }
#pragma unroll
    for (int m = 1; m <= 8; m <<= 1) {    // reduce within the 16-lane quarter
        s += __shfl_xor(s, m, 64); ss += __shfl_xor(ss, m, 64);
    }
    float mu = s * (1.f / 128.f);
    float var = ss * (1.f / 128.f) - mu * mu;
    float rstd = rsqrtf(var + 1e-5f);
    uint4 idpk = *(const uint4*)(h + node * 128 + c0);
    unsigned idw[4] = {idpk.x, idpk.y, idpk.z, idpk.w};
    uint4 pk;
    unsigned pkw[4];
#pragma unroll
    for (int w = 0; w < 4; ++w) {
        int k0 = w * 2;
        float y0 = (o[k0] - mu) * rstd * gg[c0 + k0] + bgg[c0 + k0];
        float y1 = (o[k0 + 1] - mu) * rstd * gg[c0 + k0 + 1] + bgg[c0 + k0 + 1];
        float r0 = silu(y0) + bf2f((unsigned short)(idw[w] & 0xFFFFu));
        float r1 = silu(y1) + bf2f((unsigned short)(idw[w] >> 16));
        pkw[w] = (unsigned)f2bf(r0) | ((unsigned)f2bf(r1) << 16);
    }
    pk.x = pkw[0]; pk.y = pkw[1]; pk.z = pkw[2]; pk.w = pkw[3];
    *(uint4*)(h + node * 128 + c0) = pk;
}

// ---------------- mean pool per graph (batch sorted), bf16 h -> f32 pooled ------------
__global__ void pool_kernel(const unsigned short* __restrict__ h, const int* __restrict__ batch,
                            float* __restrict__ pooled) {
    int c = threadIdx.x;
    int r0 = blockIdx.x * 64;
    int rend = r0 + 64; if (rend > NN) rend = NN;
    int cur = batch[r0];
    float acc = 0.f;
    for (int r = r0; r < rend; ++r) {
        int b = batch[r];
        float v = bf2f(h[r * 128 + c]);
        if (b != cur) {
            atomicAdd(&pooled[cur * 128 + c], acc);
            acc = 0.f; cur = b;
        }
        acc += v;
    }
    atomicAdd(&pooled[cur * 128 + c], acc);
}

// ---------------- head: silu(LN(pooled/cnt @ Wp + bp)) -> f32 out ----------------
__global__ void final_kernel(const float* __restrict__ pooled, const int* __restrict__ batch,
                             const float* __restrict__ Wp, const float* __restrict__ bp,
                             const float* __restrict__ gp, const float* __restrict__ bep,
                             float* __restrict__ out) {
    __shared__ float p[128];
    __shared__ float red[128];
    __shared__ int bounds[2];
    int g = blockIdx.x, c = threadIdx.x;
    if (c == 0) {
        int lo = 0, hi = NN;
        while (lo < hi) { int m = (lo + hi) >> 1; if (batch[m] < g) lo = m + 1; else hi = m; }
        bounds[0] = lo;
        int lo2 = lo, hi2 = NN;
        while (lo2 < hi2) { int m = (lo2 + hi2) >> 1; if (batch[m] < g + 1) lo2 = m + 1; else hi2 = m; }
        bounds[1] = lo2;
    }
    __syncthreads();
    float cnt = (float)(bounds[1] - bounds[0]); if (cnt < 1.f) cnt = 1.f;
    p[c] = pooled[g * 128 + c] / cnt;
    __syncthreads();
    float acc = bp[c];
    for (int k = 0; k < 128; ++k) acc += p[k] * Wp[k * 128 + c];
    red[c] = acc;
    __syncthreads();
    if (c < 64) {
        float s = red[c] + red[c + 64];
#pragma unroll
        for (int m = 1; m <= 32; m <<= 1) s += __shfl_xor(s, m, 64);
        if (c == 0) red[0] = s;
    }
    __syncthreads();
    float mu = red[0] * (1.f / 128.f);
    __syncthreads();
    float dv = acc - mu;
    red[c] = dv * dv;
    __syncthreads();
    if (c < 64) {
        float s = red[c] + red[c + 64];
#pragma unroll
        for (int m = 1; m <= 32; m <<= 1) s += __shfl_xor(s, m, 64);
        if (c == 0) red[0] = s;
    }
    __syncthreads();
    float var = red[0] * (1.f / 128.f);
    float rstd = rsqrtf(var + 1e-5f);
    float y = dv * rstd * gp[c] + bep[c];
    out[g * 128 + c] = silu(y);
}

extern "C" void kernel_launch(void* const* d_in, const int* in_sizes, int n_in,
                              void* d_out, int out_size, void* d_ws, size_t ws_size,
                              hipStream_t stream) {
    const float* x    = (const float*)d_in[0];
    const int*   eidx = (const int*)d_in[1];
    const int*   batch= (const int*)d_in[2];
    const float* W0   = (const float*)d_in[3];
    const float* b0   = (const float*)d_in[4];
    const float* g0   = (const float*)d_in[5];
    const float* be0  = (const float*)d_in[6];
    const float* Wg   = (const float*)d_in[7];
    const float* atts = (const float*)d_in[8];
    const float* attd = (const float*)d_in[9];
    const float* bg   = (const float*)d_in[10];
    const float* gg   = (const float*)d_in[11];
    const float* bgg  = (const float*)d_in[12];
    const float* Wp   = (const float*)d_in[13];
    const float* bp   = (const float*)d_in[14];
    const float* gp   = (const float*)d_in[15];
    const float* bep  = (const float*)d_in[16];

    char* ws = (char*)d_ws;
    size_t off = 0;
    auto alloc = [&](size_t bytes) {
        void* p = ws + off;
        off = (off + bytes + 255) & ~(size_t)255;
        return p;
    };
    unsigned short* h        = (unsigned short*)alloc((size_t)NPAD * 128 * 2);
    unsigned char*  hh8      = (unsigned char*)alloc((size_t)NN * 128);
    float*          a_s      = (float*)alloc((size_t)NN * 4 * 4);
    float*          a_d      = (float*)alloc((size_t)NN * 4 * 4);
    float*          es       = (float*)alloc((size_t)NN * 4 * 4);
    int*            offs     = (int*)alloc((size_t)(NN + 1) * 4);
    int*            csr      = (int*)alloc((size_t)EPE * 4);
    unsigned*       binned   = (unsigned*)alloc((size_t)EPE * 4);
    int*            hist_blk = (int*)alloc((size_t)NBLK * NB * 4);
    int*            blkOfs   = (int*)alloc((size_t)NBLK * NB * 4);
    int*            bktBase  = (int*)alloc((size_t)(NB + 1) * 4);
    unsigned short* WT       = (unsigned short*)alloc(4 * 16384 * 2);
    float*          pooled   = (float*)alloc((size_t)BGR * 128 * 4);

    transpose_zero<<<4 + 32, 256, 0, stream>>>(W0, Wg, WT, pooled);
    bucket_hist<<<NBLK, 256, 0, stream>>>(eidx, hist_blk);
    scan_buckets<<<1, 128, 0, stream>>>(hist_blk, blkOfs, bktBase);
    bin_edges<<<NBLK, 256, 0, stream>>>(eidx, blkOfs, binned);
    build_csr<<<NB, 256, 0, stream>>>(binned, bktBase, offs, csr);

    gemm_encoder<<<NPAD / 64, 256, 0, stream>>>(x, WT, b0, g0, be0, h);
    for (int l = 0; l < 3; ++l) {
        gemm_gat<<<NPAD / 64, 256, 0, stream>>>(h, WT + (l + 1) * 16384,
                                                atts + l * 128, attd + l * 128,
                                                hh8, a_s, a_d, es);
        gat_aggregate<<<NN / 16, 256, 0, stream>>>(offs, csr, a_s, a_d, es, hh8, h,
                                                   bg + l * 128, gg + l * 128,
                                                   bgg + l * 128);
    }
    pool_kernel<<<(NN + 63) / 64, 128, 0, stream>>>(h, batch, pooled);
    final_kernel<<<BGR, 128, 0, stream>>>(pooled, batch, Wp, bp, gp, bep, (float*)d_out);
}

// Round 16
// 383.650 us; speedup vs baseline: 1.0332x; 1.0332x over previous
//
#include <hip/hip_runtime.h>

#define NN    50000
#define EE    800000
#define EPE   850000     // EE + NN self loops
#define NPAD  50048      // multiple of 64
#define BGR   64
#define MAXCH 128        // edge chunk per node held in LDS (aggregate)
#define NB    98         // buckets of 512 nodes
#define CHUNK 4096       // edges per binning block
#define NBLK  208        // ceil(EPE / CHUNK)
#define BCAP  12288      // per-bucket LDS capacity in build_csr

typedef __attribute__((ext_vector_type(8))) short bf16x8;
typedef __attribute__((ext_vector_type(4))) float f32x4;
typedef __attribute__((ext_vector_type(2))) float f32x2;

__device__ __forceinline__ float bf2f(unsigned short u) {
    return __uint_as_float(((unsigned)u) << 16);
}
__device__ __forceinline__ unsigned short f2bf(float f) {
    unsigned u = __float_as_uint(f);
    unsigned r = (u + 0x7FFFu + ((u >> 16) & 1u)) >> 16;
    return (unsigned short)r;
}
__device__ __forceinline__ float silu(float y) { return y / (1.f + __expf(-y)); }

// -- fused: weight transpose (blk 0-3) + pooled zero (blk 4..35) --
__global__ void transpose_zero(const float* __restrict__ W0, const float* __restrict__ Wg,
                               unsigned short* __restrict__ WT, float* __restrict__ pooled) {
    __shared__ unsigned short tile[128][129];
    int b = blockIdx.x;
    if (b < 4) {
        const float* src = (b == 0) ? W0 : (Wg + (b - 1) * 16384);
        unsigned short* dst = WT + b * 16384;
        for (int i = threadIdx.x; i < 16384; i += 256) tile[i >> 7][i & 127] = f2bf(src[i]);
        __syncthreads();
        for (int i = threadIdx.x; i < 16384; i += 256) {
            int c = i >> 7, k = i & 127;
            dst[i] = tile[k][c];
        }
    } else {
        int j = (b - 4) * 256 + threadIdx.x;
        if (j < BGR * 128) pooled[j] = 0.f;
    }
}

// ---------------- per-chunk bucket histograms (LDS only, no global atomics) -----------
__global__ __launch_bounds__(256) void bucket_hist(const int* __restrict__ eidx,
                                                   int* __restrict__ hist_blk) {
    __shared__ int lh[NB];
    for (int t = threadIdx.x; t < NB; t += 256) lh[t] = 0;
    __syncthreads();
    int base = blockIdx.x * CHUNK;
#pragma unroll
    for (int j = 0; j < CHUNK / 256; ++j) {
        int i = base + j * 256 + threadIdx.x;
        if (i < EPE) {
            int d = (i < EE) ? eidx[EE + i] : (i - EE);
            atomicAdd(&lh[d >> 9], 1);
        }
    }
    __syncthreads();
    for (int t = threadIdx.x; t < NB; t += 256)
        hist_blk[blockIdx.x * NB + t] = lh[t];
}

// ------- bucket totals -> per-block per-bucket offsets + bucketBase -------------------
__global__ void scan_buckets(const int* __restrict__ hist_blk, int* __restrict__ blkOfs,
                             int* __restrict__ bucketBase) {
    __shared__ int tot[NB];
    __shared__ int base[NB];
    int t = threadIdx.x;
    if (t < NB) {
        int s = 0;
        for (int k = 0; k < NBLK; ++k) s += hist_blk[k * NB + t];
        tot[t] = s;
    }
    __syncthreads();
    if (t == 0) {
        int run = 0;
        for (int b = 0; b < NB; ++b) { base[b] = run; run += tot[b]; }
        bucketBase[NB] = EPE;
    }
    __syncthreads();
    if (t < NB) {
        int run = base[t];
        bucketBase[t] = run;
        for (int k = 0; k < NBLK; ++k) {
            blkOfs[k * NB + t] = run;
            run += hist_blk[k * NB + t];
        }
    }
}

// ---------------- bin edges into bucket-grouped array (no global atomics) ----------
__global__ __launch_bounds__(256) void bin_edges(const int* __restrict__ eidx,
                                                 const int* __restrict__ blkOfs,
                                                 unsigned* __restrict__ binned) {
    __shared__ unsigned staged[CHUNK];
    __shared__ int lhist[NB];
    __shared__ int lscan[NB];
    __shared__ int cnt2[NB];
    __shared__ int gofs[NB];
    int tid = threadIdx.x;
    for (int t = tid; t < NB; t += 256) { lhist[t] = 0; cnt2[t] = 0; }
    __syncthreads();
    int base = blockIdx.x * CHUNK;
    unsigned pk[CHUNK / 256];
#pragma unroll
    for (int j = 0; j < CHUNK / 256; ++j) {
        int i = base + j * 256 + tid;
        pk[j] = 0xFFFFFFFFu;
        if (i < EPE) {
            int s, d;
            if (i < EE) { s = eidx[i]; d = eidx[EE + i]; } else { s = i - EE; d = i - EE; }
            pk[j] = ((unsigned)s << 16) | (unsigned)d;
            atomicAdd(&lhist[d >> 9], 1);
        }
    }
    __syncthreads();
    if (tid == 0) {
        int run = 0;
        for (int b = 0; b < NB; ++b) { lscan[b] = run; run += lhist[b]; }
    }
    __syncthreads();
#pragma unroll
    for (int j = 0; j < CHUNK / 256; ++j) {
        if (pk[j] != 0xFFFFFFFFu) {
            int b = (int)((pk[j] & 0xFFFFu) >> 9);
            int lp = lscan[b] + atomicAdd(&cnt2[b], 1);
            staged[lp] = pk[j];
        }
    }
    for (int t = tid; t < NB; t += 256) gofs[t] = blkOfs[blockIdx.x * NB + t];
    __syncthreads();
    int nTot = lscan[NB - 1] + lhist[NB - 1];
    for (int i = tid; i < nTot; i += 256) {
        unsigned p = staged[i];
        int b = (int)((p & 0xFFFFu) >> 9);
        binned[gofs[b] + (i - lscan[b])] = p;
    }
}

// ------- per-bucket: local node counts -> offs + in-LDS sort -> contiguous csr --------
__global__ __launch_bounds__(256) void build_csr(const unsigned* __restrict__ binned,
                                                 const int* __restrict__ bucketBase,
                                                 int* __restrict__ offs,
                                                 int* __restrict__ csr) {
    __shared__ int lcsr[BCAP];
    __shared__ int lcnt[512];
    __shared__ int lofs[512];
    __shared__ int lcur[512];
    __shared__ int psum[256];
    int b = blockIdx.x, tid = threadIdx.x;
    int n0 = b * 512;
    int o0 = bucketBase[b];
    int nTot = bucketBase[b + 1] - o0;
    if (nTot > BCAP) nTot = BCAP;
    for (int j = tid; j < 512; j += 256) lcnt[j] = 0;
    __syncthreads();
    for (int i = tid; i < nTot; i += 256)
        atomicAdd(&lcnt[binned[o0 + i] & 511u], 1);
    __syncthreads();
    int a0 = lcnt[2 * tid], a1 = lcnt[2 * tid + 1];
    psum[tid] = a0 + a1;
    __syncthreads();
    for (int d = 1; d < 256; d <<= 1) {
        int v = (tid >= d) ? psum[tid - d] : 0;
        __syncthreads(); psum[tid] += v; __syncthreads();
    }
    int exclPair = psum[tid] - (a0 + a1);
    lofs[2 * tid] = exclPair;
    lofs[2 * tid + 1] = exclPair + a0;
    lcur[2 * tid] = exclPair;
    lcur[2 * tid + 1] = exclPair + a0;
    __syncthreads();
    for (int j = tid; j < 512; j += 256) {
        int node = n0 + j;
        if (node < NN) offs[node] = o0 + lofs[j];
    }
    if (b == 0 && tid == 0) offs[NN] = EPE;
    for (int i = tid; i < nTot; i += 256) {
        unsigned p = binned[o0 + i];
        int pos = atomicAdd(&lcur[p & 511u], 1);
        if (pos < BCAP) lcsr[pos] = (int)(p >> 16);
    }
    __syncthreads();
    for (int i = tid; i < nTot; i += 256)
        csr[o0 + i] = lcsr[i];
}

// ---------------- encoder GEMM: h(bf16) = silu(LN(x@W0 + b0)) ----------------
__global__ __launch_bounds__(256) void gemm_encoder(
    const float* __restrict__ x, const unsigned short* __restrict__ WT,
    const float* __restrict__ b0, const float* __restrict__ g0,
    const float* __restrict__ be0, unsigned short* __restrict__ h) {
    int wave = threadIdx.x >> 6, lane = threadIdx.x & 63;
    int cl = lane & 15, q = lane >> 4;
    int row0 = blockIdx.x * 64 + wave * 16;
    int rA = row0 + cl; if (rA >= NN) rA = NN - 1;
    int kq = q * 8;
    f32x4 acc[8];
#pragma unroll
    for (int t = 0; t < 8; ++t) acc[t] = (f32x4){0.f, 0.f, 0.f, 0.f};
#pragma unroll
    for (int k0 = 0; k0 < 128; k0 += 32) {
        const float* xr = x + rA * 128 + k0 + kq;
        f32x4 f0 = *(const f32x4*)(xr);
        f32x4 f1 = *(const f32x4*)(xr + 4);
        bf16x8 a;
#pragma unroll
        for (int j = 0; j < 4; ++j) {
            a[j] = (short)f2bf(f0[j]);
            a[4 + j] = (short)f2bf(f1[j]);
        }
#pragma unroll
        for (int t = 0; t < 8; ++t) {
            bf16x8 b = *(const bf16x8*)(WT + (t * 16 + cl) * 128 + k0 + kq);
            acc[t] = __builtin_amdgcn_mfma_f32_16x16x32_bf16(a, b, acc[t], 0, 0, 0);
        }
    }
    float bcol[8], gcol[8], becol[8];
#pragma unroll
    for (int t = 0; t < 8; ++t) {
        int c = t * 16 + cl;
        bcol[t] = b0[c]; gcol[t] = g0[c]; becol[t] = be0[c];
    }
#pragma unroll
    for (int r = 0; r < 4; ++r) {
        int row = row0 + q * 4 + r;
        float v[8], s = 0.f, ss = 0.f;
#pragma unroll
        for (int t = 0; t < 8; ++t) {
            v[t] = acc[t][r] + bcol[t];
            s += v[t]; ss += v[t] * v[t];
        }
#pragma unroll
        for (int m = 1; m <= 8; m <<= 1) {
            s += __shfl_xor(s, m, 64); ss += __shfl_xor(ss, m, 64);
        }
        float mu = s * (1.f / 128.f);
        float var = ss * (1.f / 128.f) - mu * mu;
        float rstd = rsqrtf(var + 1e-5f);
        if (row < NN) {
#pragma unroll
            for (int t = 0; t < 8; ++t) {
                float y = (v[t] - mu) * rstd * gcol[t] + becol[t];
                h[row * 128 + t * 16 + cl] = f2bf(silu(y));
            }
        }
    }
}

// ---------------- GAT GEMM: hh(fp8 e4m3) = h@Wg[l], a_s/a_d/es per node --------------
__global__ __launch_bounds__(256) void gemm_gat(
    const unsigned short* __restrict__ h, const unsigned short* __restrict__ WT,
    const float* __restrict__ atts, const float* __restrict__ attd,
    unsigned char* __restrict__ hh8, float* __restrict__ a_s, float* __restrict__ a_d,
    float* __restrict__ es) {
    int wave = threadIdx.x >> 6, lane = threadIdx.x & 63;
    int cl = lane & 15, q = lane >> 4;
    int row0 = blockIdx.x * 64 + wave * 16;
    int rA = row0 + cl; if (rA >= NN) rA = NN - 1;
    int kq = q * 8;
    f32x4 acc[8];
#pragma unroll
    for (int t = 0; t < 8; ++t) acc[t] = (f32x4){0.f, 0.f, 0.f, 0.f};
#pragma unroll
    for (int k0 = 0; k0 < 128; k0 += 32) {
        bf16x8 a = *(const bf16x8*)(h + rA * 128 + k0 + kq);
#pragma unroll
        for (int t = 0; t < 8; ++t) {
            bf16x8 b = *(const bf16x8*)(WT + (t * 16 + cl) * 128 + k0 + kq);
            acc[t] = __builtin_amdgcn_mfma_f32_16x16x32_bf16(a, b, acc[t], 0, 0, 0);
        }
    }
#pragma unroll
    for (int r = 0; r < 4; ++r) {
        int row = row0 + q * 4 + r;
        if (row < NN) {
#pragma unroll
            for (int t = 0; t < 8; ++t) {
                unsigned pk = (unsigned)__builtin_amdgcn_cvt_pk_fp8_f32(acc[t][r], acc[t][r], 0, false);
                hh8[row * 128 + t * 16 + cl] = (unsigned char)(pk & 0xFFu);
            }
        }
    }
    float as_lo[4], as_hi[4], ad_lo[4], ad_hi[4];
#pragma unroll
    for (int hd = 0; hd < 4; ++hd) {
        as_lo[hd] = atts[hd * 32 + cl];      as_hi[hd] = atts[hd * 32 + 16 + cl];
        ad_lo[hd] = attd[hd * 32 + cl];      ad_hi[hd] = attd[hd * 32 + 16 + cl];
    }
#pragma unroll
    for (int r = 0; r < 4; ++r) {
        int row = row0 + q * 4 + r;
        float ps[4], pd[4];
#pragma unroll
        for (int hd = 0; hd < 4; ++hd) {
            float v0 = acc[2 * hd][r], v1 = acc[2 * hd + 1][r];
            ps[hd] = v0 * as_lo[hd] + v1 * as_hi[hd];
            pd[hd] = v0 * ad_lo[hd] + v1 * ad_hi[hd];
        }
#pragma unroll
        for (int m = 1; m <= 8; m <<= 1) {
#pragma unroll
            for (int hd = 0; hd < 4; ++hd) {
                ps[hd] += __shfl_xor(ps[hd], m, 64);
                pd[hd] += __shfl_xor(pd[hd], m, 64);
            }
        }
        if (row < NN && cl < 4) {
            float vs = (cl == 0) ? ps[0] : (cl == 1) ? ps[1] : (cl == 2) ? ps[2] : ps[3];
            float vd = (cl == 0) ? pd[0] : (cl == 1) ? pd[1] : (cl == 2) ? pd[2] : pd[3];
            a_s[row * 4 + cl] = vs;
            a_d[row * 4 + cl] = vd;
            float e = vs + vd;                       // self-loop logit
            es[row * 4 + cl] = (e > 0.f) ? e : 0.2f * e;
        }
    }
}

// ---------------- aggregation: 2 nodes per wave (8/block), fp8 hh gather --------------
__global__ __launch_bounds__(256) void gat_aggregate(
    const int* __restrict__ offs, const int* __restrict__ csr,
    const float* __restrict__ a_s, const float* __restrict__ a_d,
    const float* __restrict__ es, const unsigned char* __restrict__ hh8,
    unsigned short* __restrict__ h,
    const float* __restrict__ bg, const float* __restrict__ gg,
    const float* __restrict__ bgg) {
    __shared__ f32x4 lw[8][MAXCH];
    int wv = threadIdx.x >> 6;
    int lane = threadIdx.x & 63;
    int half = lane >> 5;
    int l32 = lane & 31;
    int ns = wv * 2 + half;
    int node = blockIdx.x * 8 + ns;     // NN % 8 == 0
    int e0 = offs[node], e1 = offs[node + 1];
    int c0 = l32 * 4;
    int hd = l32 >> 3;
    f32x4 ad4 = *(const f32x4*)(a_d + node * 4);
    f32x4 e4  = *(const f32x4*)(es  + node * 4);
    float dacc[4];
    f32x4 xacc[4];
#pragma unroll
    for (int u = 0; u < 4; ++u) {
        dacc[u] = 0.f;
        xacc[u] = (f32x4){0.f, 0.f, 0.f, 0.f};
    }
    for (int base = e0; base < e1; base += MAXCH) {
        int cend = min(e1, base + MAXCH);
        for (int e = base + l32; e < cend; e += 32) {
            int s = csr[e];
            f32x4 as = *(const f32x4*)(a_s + s * 4);
            f32x4 o;
#pragma unroll
            for (int k = 0; k < 4; ++k) {
                float qq = as[k] + ad4[k];
                qq = (qq > 0.f) ? qq : 0.2f * qq;
                o[k] = __expf(qq - e4[k]);
            }
            lw[ns][e - base] = o;
        }
        asm volatile("s_waitcnt lgkmcnt(0)" ::: "memory");
        int n = cend - base;
        int j = 0;
        for (; j + 4 <= n; j += 4) {
            int s0 = csr[base + j], s1 = csr[base + j + 1];
            int s2 = csr[base + j + 2], s3 = csr[base + j + 3];
            float w0 = lw[ns][j + 0][hd];
            float w1 = lw[ns][j + 1][hd];
            float w2 = lw[ns][j + 2][hd];
            float w3 = lw[ns][j + 3][hd];
            unsigned v0 = *(const unsigned*)(hh8 + s0 * 128 + c0);
            unsigned v1 = *(const unsigned*)(hh8 + s1 * 128 + c0);
            unsigned v2 = *(const unsigned*)(hh8 + s2 * 128 + c0);
            unsigned v3 = *(const unsigned*)(hh8 + s3 * 128 + c0);
            f32x2 l0 = __builtin_amdgcn_cvt_pk_f32_fp8(v0, false);
            f32x2 h0 = __builtin_amdgcn_cvt_pk_f32_fp8(v0, true);
            f32x2 l1 = __builtin_amdgcn_cvt_pk_f32_fp8(v1, false);
            f32x2 h1 = __builtin_amdgcn_cvt_pk_f32_fp8(v1, true);
            f32x2 l2 = __builtin_amdgcn_cvt_pk_f32_fp8(v2, false);
            f32x2 h2 = __builtin_amdgcn_cvt_pk_f32_fp8(v2, true);
            f32x2 l3 = __builtin_amdgcn_cvt_pk_f32_fp8(v3, false);
            f32x2 h3 = __builtin_amdgcn_cvt_pk_f32_fp8(v3, true);
            dacc[0] += w0;
            xacc[0][0] += w0 * l0[0]; xacc[0][1] += w0 * l0[1];
            xacc[0][2] += w0 * h0[0]; xacc[0][3] += w0 * h0[1];
            dacc[1] += w1;
            xacc[1][0] += w1 * l1[0]; xacc[1][1] += w1 * l1[1];
            xacc[1][2] += w1 * h1[0]; xacc[1][3] += w1 * h1[1];
            dacc[2] += w2;
            xacc[2][0] += w2 * l2[0]; xacc[2][1] += w2 * l2[1];
            xacc[2][2] += w2 * h2[0]; xacc[2][3] += w2 * h2[1];
            dacc[3] += w3;
            xacc[3][0] += w3 * l3[0]; xacc[3][1] += w3 * l3[1];
            xacc[3][2] += w3 * h3[0]; xacc[3][3] += w3 * h3[1];
        }
        for (; j < n; ++j) {
            int s0 = csr[base + j];
            float w0 = lw[ns][j][hd];
            unsigned v0 = *(const unsigned*)(hh8 + s0 * 128 + c0);
            f32x2 l0 = __builtin_amdgcn_cvt_pk_f32_fp8(v0, false);
            f32x2 h0 = __builtin_amdgcn_cvt_pk_f32_fp8(v0, true);
            dacc[0] += w0;
            xacc[0][0] += w0 * l0[0]; xacc[0][1] += w0 * l0[1];
            xacc[0][2] += w0 * h0[0]; xacc[0][3] += w0 * h0[1];
        }
        if (cend < e1)
            asm volatile("s_waitcnt lgkmcnt(0)" ::: "memory");
    }
    float den = (dacc[0] + dacc[1]) + (dacc[2] + dacc[3]);
    f32x4 X;
#pragma unroll
    for (int k = 0; k < 4; ++k)
        X[k] = (xacc[0][k] + xacc[1][k]) + (xacc[2][k] + xacc[3][k]);
    float inv = 1.f / den;
    f32x4 bgv  = *(const f32x4*)(bg + c0);
    f32x4 ggv  = *(const f32x4*)(gg + c0);
    f32x4 bggv = *(const f32x4*)(bgg + c0);
    f32x4 o;
    float s = 0.f, ss = 0.f;
#pragma unroll
    for (int k = 0; k < 4; ++k) {
        o[k] = X[k] * inv + bgv[k];
        s += o[k]; ss += o[k] * o[k];
    }
#pragma unroll
    for (int m = 1; m <= 16; m <<= 1) {   // reduce within the 32-lane half
        s += __shfl_xor(s, m, 64); ss += __shfl_xor(ss, m, 64);
    }
    float mu = s * (1.f / 128.f);
    float var = ss * (1.f / 128.f) - mu * mu;
    float rstd = rsqrtf(var + 1e-5f);
    uint2 idpk = *(const uint2*)(h + node * 128 + c0);
    float r0 = silu((o[0] - mu) * rstd * ggv[0] + bggv[0]) + bf2f((unsigned short)(idpk.x & 0xFFFFu));
    float r1 = silu((o[1] - mu) * rstd * ggv[1] + bggv[1]) + bf2f((unsigned short)(idpk.x >> 16));
    float r2 = silu((o[2] - mu) * rstd * ggv[2] + bggv[2]) + bf2f((unsigned short)(idpk.y & 0xFFFFu));
    float r3 = silu((o[3] - mu) * rstd * ggv[3] + bggv[3]) + bf2f((unsigned short)(idpk.y >> 16));
    uint2 pk;
    pk.x = (unsigned)f2bf(r0) | ((unsigned)f2bf(r1) << 16);
    pk.y = (unsigned)f2bf(r2) | ((unsigned)f2bf(r3) << 16);
    *(uint2*)(h + node * 128 + c0) = pk;
}

// ---------------- mean pool per graph (batch sorted), bf16 h -> f32 pooled ------------
__global__ void pool_kernel(const unsigned short* __restrict__ h, const int* __restrict__ batch,
                            float* __restrict__ pooled) {
    int c = threadIdx.x;
    int r0 = blockIdx.x * 64;
    int rend = r0 + 64; if (rend > NN) rend = NN;
    int cur = batch[r0];
    float acc = 0.f;
    for (int r = r0; r < rend; ++r) {
        int b = batch[r];
        float v = bf2f(h[r * 128 + c]);
        if (b != cur) {
            atomicAdd(&pooled[cur * 128 + c], acc);
            acc = 0.f; cur = b;
        }
        acc += v;
    }
    atomicAdd(&pooled[cur * 128 + c], acc);
}

// ---------------- head: silu(LN(pooled/cnt @ Wp + bp)) -> f32 out ----------------
__global__ void final_kernel(const float* __restrict__ pooled, const int* __restrict__ batch,
                             const float* __restrict__ Wp, const float* __restrict__ bp,
                             const float* __restrict__ gp, const float* __restrict__ bep,
                             float* __restrict__ out) {
    __shared__ float p[128];
    __shared__ float red[128];
    __shared__ int bounds[2];
    int g = blockIdx.x, c = threadIdx.x;
    if (c == 0) {
        int lo = 0, hi = NN;
        while (lo < hi) { int m = (lo + hi) >> 1; if (batch[m] < g) lo = m + 1; else hi = m; }
        bounds[0] = lo;
        int lo2 = lo, hi2 = NN;
        while (lo2 < hi2) { int m = (lo2 + hi2) >> 1; if (batch[m] < g + 1) lo2 = m + 1; else hi2 = m; }
        bounds[1] = lo2;
    }
    __syncthreads();
    float cnt = (float)(bounds[1] - bounds[0]); if (cnt < 1.f) cnt = 1.f;
    p[c] = pooled[g * 128 + c] / cnt;
    __syncthreads();
    float acc = bp[c];
    for (int k = 0; k < 128; ++k) acc += p[k] * Wp[k * 128 + c];
    red[c] = acc;
    __syncthreads();
    if (c < 64) {
        float s = red[c] + red[c + 64];
#pragma unroll
        for (int m = 1; m <= 32; m <<= 1) s += __shfl_xor(s, m, 64);
        if (c == 0) red[0] = s;
    }
    __syncthreads();
    float mu = red[0] * (1.f / 128.f);
    __syncthreads();
    float dv = acc - mu;
    red[c] = dv * dv;
    __syncthreads();
    if (c < 64) {
        float s = red[c] + red[c + 64];
#pragma unroll
        for (int m = 1; m <= 32; m <<= 1) s += __shfl_xor(s, m, 64);
        if (c == 0) red[0] = s;
    }
    __syncthreads();
    float var = red[0] * (1.f / 128.f);
    float rstd = rsqrtf(var + 1e-5f);
    float y = dv * rstd * gp[c] + bep[c];
    out[g * 128 + c] = silu(y);
}

extern "C" void kernel_launch(void* const* d_in, const int* in_sizes, int n_in,
                              void* d_out, int out_size, void* d_ws, size_t ws_size,
                              hipStream_t stream) {
    const float* x    = (const float*)d_in[0];
    const int*   eidx = (const int*)d_in[1];
    const int*   batch= (const int*)d_in[2];
    const float* W0   = (const float*)d_in[3];
    const float* b0   = (const float*)d_in[4];
    const float* g0   = (const float*)d_in[5];
    const float* be0  = (const float*)d_in[6];
    const float* Wg   = (const float*)d_in[7];
    const float* atts = (const float*)d_in[8];
    const float* attd = (const float*)d_in[9];
    const float* bg   = (const float*)d_in[10];
    const float* gg   = (const float*)d_in[11];
    const float* bgg  = (const float*)d_in[12];
    const float* Wp   = (const float*)d_in[13];
    const float* bp   = (const float*)d_in[14];
    const float* gp   = (const float*)d_in[15];
    const float* bep  = (const float*)d_in[16];

    char* ws = (char*)d_ws;
    size_t off = 0;
    auto alloc = [&](size_t bytes) {
        void* p = ws + off;
        off = (off + bytes + 255) & ~(size_t)255;
        return p;
    };
    unsigned short* h        = (unsigned short*)alloc((size_t)NPAD * 128 * 2);
    unsigned char*  hh8      = (unsigned char*)alloc((size_t)NN * 128);
    float*          a_s      = (float*)alloc((size_t)NN * 4 * 4);
    float*          a_d      = (float*)alloc((size_t)NN * 4 * 4);
    float*          es       = (float*)alloc((size_t)NN * 4 * 4);
    int*            offs     = (int*)alloc((size_t)(NN + 1) * 4);
    int*            csr      = (int*)alloc((size_t)EPE * 4);
    unsigned*       binned   = (unsigned*)alloc((size_t)EPE * 4);
    int*            hist_blk = (int*)alloc((size_t)NBLK * NB * 4);
    int*            blkOfs   = (int*)alloc((size_t)NBLK * NB * 4);
    int*            bktBase  = (int*)alloc((size_t)(NB + 1) * 4);
    unsigned short* WT       = (unsigned short*)alloc(4 * 16384 * 2);
    float*          pooled   = (float*)alloc((size_t)BGR * 128 * 4);

    transpose_zero<<<4 + 32, 256, 0, stream>>>(W0, Wg, WT, pooled);
    bucket_hist<<<NBLK, 256, 0, stream>>>(eidx, hist_blk);
    scan_buckets<<<1, 128, 0, stream>>>(hist_blk, blkOfs, bktBase);
    bin_edges<<<NBLK, 256, 0, stream>>>(eidx, blkOfs, binned);
    build_csr<<<NB, 256, 0, stream>>>(binned, bktBase, offs, csr);

    gemm_encoder<<<NPAD / 64, 256, 0, stream>>>(x, WT, b0, g0, be0, h);
    for (int l = 0; l < 3; ++l) {
        gemm_gat<<<NPAD / 64, 256, 0, stream>>>(h, WT + (l + 1) * 16384,
                                                atts + l * 128, attd + l * 128,
                                                hh8, a_s, a_d, es);
        gat_aggregate<<<NN / 8, 256, 0, stream>>>(offs, csr, a_s, a_d, es, hh8, h,
                                                  bg + l * 128, gg + l * 128,
                                                  bgg + l * 128);
    }
    pool_kernel<<<(NN + 63) / 64, 128, 0, stream>>>(h, batch, pooled);
    final_kernel<<<BGR, 128, 0, stream>>>(pooled, batch, Wp, bp, gp, bep, (float*)d_out);
}